// Round 2
// baseline (755.939 us; speedup 1.0000x reference)
//
#include <hip/hip_runtime.h>
#include <hip/hip_bf16.h>

#define E_CNT 800000
#define N_CNT 50000
#define EB 64                      // edges per block-iteration (4 sub-tiles of 16)
#define E_TILES64 (E_CNT / EB)     // 12500
#define N_TILES (N_CNT / 16)       // 3125
#define SCAN_BLOCKS 196            // ceil(50000 / 256)

// ---- workspace layout (bytes) ----
#define WS_COUNTS  0
#define WS_OFFSETS 204800
#define WS_CURSOR  409600
#define WS_BSUM    614400
#define WS_EIDS    615424

typedef __attribute__((ext_vector_type(8))) short bf16x8;   // MFMA A/B frag (8 bf16)
typedef __attribute__((ext_vector_type(4))) short short4v;  // 4 bf16 packed store
typedef __attribute__((ext_vector_type(4))) float f32x4;    // MFMA C/D frag / float4

static __device__ __forceinline__ short f2bf(float v) {
    union { __hip_bfloat16 b; short u; } cv;
    cv.b = __float2bfloat16(v);
    return cv.u;
}

// ---------------- CSR build: histogram -> scan -> scatter ----------------

__global__ void hist_kernel(const int* __restrict__ eidx, int* __restrict__ counts) {
    int stride = gridDim.x * blockDim.x;
    for (int i = blockIdx.x * blockDim.x + threadIdx.x; i < E_CNT; i += stride) {
        int d = eidx[E_CNT + i];
        if ((unsigned)d >= (unsigned)N_CNT) d = 0;
        atomicAdd(&counts[d], 1);
    }
}

__global__ void scan_block_sums(const int* __restrict__ counts, int* __restrict__ bsum) {
    __shared__ int s[256];
    int t = threadIdx.x;
    int i = blockIdx.x * 256 + t;
    s[t] = (i < N_CNT) ? counts[i] : 0;
    __syncthreads();
    #pragma unroll
    for (int off = 128; off; off >>= 1) {
        if (t < off) s[t] += s[t + off];
        __syncthreads();
    }
    if (t == 0) bsum[blockIdx.x] = s[0];
}

__global__ void scan_top(int* __restrict__ bsum) {
    __shared__ int s[256];
    int t = threadIdx.x;
    int mine = (t < SCAN_BLOCKS) ? bsum[t] : 0;
    s[t] = mine;
    __syncthreads();
    #pragma unroll
    for (int off = 1; off < 256; off <<= 1) {
        int v = (t >= off) ? s[t - off] : 0;
        __syncthreads();
        s[t] += v;
        __syncthreads();
    }
    if (t < SCAN_BLOCKS) bsum[t] = s[t] - mine;   // inclusive -> exclusive
}

__global__ void scan_within(const int* __restrict__ counts, const int* __restrict__ bsum,
                            int* __restrict__ offsets, int* __restrict__ cursor) {
    __shared__ int s[256];
    int t = threadIdx.x;
    int i = blockIdx.x * 256 + t;
    int mine = (i < N_CNT) ? counts[i] : 0;
    s[t] = mine;
    __syncthreads();
    #pragma unroll
    for (int off = 1; off < 256; off <<= 1) {
        int v = (t >= off) ? s[t - off] : 0;
        __syncthreads();
        s[t] += v;
        __syncthreads();
    }
    if (i < N_CNT) {
        int o = bsum[blockIdx.x] + s[t] - mine;   // exclusive prefix
        offsets[i] = o;
        cursor[i]  = o;
    }
}

__global__ void scatter_kernel(const int* __restrict__ eidx, int* __restrict__ cursor,
                               int* __restrict__ edge_ids) {
    int stride = gridDim.x * blockDim.x;
    for (int i = blockIdx.x * blockDim.x + threadIdx.x; i < E_CNT; i += stride) {
        int d = eidx[E_CNT + i];
        if ((unsigned)d >= (unsigned)N_CNT) d = 0;
        int pos = atomicAdd(&cursor[d], 1);
        edge_ids[pos] = i;
    }
}

// ---------------- edge kernel: 64-edge tiles, pipelined staging ----------------
// 4 waves cooperate on a 64-edge tile (4 sub-tiles of 16 edges).
// Swapped-operand MFMA: GEMM1 h^T = W1^T(A,regs) * edge_in^T(B,LDS), K=192;
// GEMM2 out^T = W2^T(A,regs) * h^T(B,LDS), K=128.
// Loop structure (2 barriers/tile): GEMM1 | barrier | GEMM2+stage(next) | barrier.
__launch_bounds__(256, 3)
__global__ void edge_kernel(const float* __restrict__ x,
                            const int* __restrict__ eidx,
                            const float* __restrict__ eattr,
                            const float* __restrict__ w1, const float* __restrict__ b1,
                            const float* __restrict__ w2, const float* __restrict__ b2,
                            float* __restrict__ eout) {
    __shared__ short s_in[EB][200];   // edge_in rows bf16 (192 + 8 pad)  25.6 KB
    __shared__ short s_h[EB][136];    // h rows bf16 (128 + 8 pad)        17.4 KB

    const int tid  = threadIdx.x;
    const int wave = tid >> 6;
    const int l15  = tid & 15;
    const int q    = (tid & 63) >> 4;

    // ---- weight fragments -> registers (once per block), fp32 -> bf16 ----
    bf16x8 a1[2][6];
    #pragma unroll
    for (int t = 0; t < 2; t++)
        #pragma unroll
        for (int k0 = 0; k0 < 6; k0++)
            #pragma unroll
            for (int j = 0; j < 8; j++)
                a1[t][k0][j] = f2bf(w1[(k0 * 32 + q * 8 + j) * 128 + (wave * 32 + t * 16 + l15)]);
    bf16x8 a2[4];
    #pragma unroll
    for (int k0 = 0; k0 < 4; k0++)
        #pragma unroll
        for (int j = 0; j < 8; j++)
            a2[k0][j] = f2bf(w2[(k0 * 32 + q * 8 + j) * 64 + (wave * 16 + l15)]);
    f32x4 bias1[2];
    #pragma unroll
    for (int t = 0; t < 2; t++)
        #pragma unroll
        for (int r = 0; r < 4; r++)
            bias1[t][r] = b1[wave * 32 + t * 16 + q * 4 + r];
    f32x4 bias2;
    #pragma unroll
    for (int r = 0; r < 4; r++) bias2[r] = b2[wave * 16 + q * 4 + r];

    // stage edge_in = [eattr | x[src] | x[dst]] for 64 rows: 64 x 48 float4-chunks,
    // fp32 global -> bf16 LDS. 12 independent chunks per thread.
    auto stage = [&](int tile) {
        const int e0 = tile * EB;
        #pragma unroll
        for (int i = 0; i < 12; i++) {
            int c  = tid + 256 * i;            // 0..3071
            int el = c / 48, p = c - el * 48;  // el: row 0..63, p: float4 idx in row
            const float* src;
            if (p < 16) {
                src = eattr + (long)(e0 + el) * 64 + p * 4;
            } else {
                int id = eidx[(p < 32 ? 0 : E_CNT) + e0 + el];
                if ((unsigned)id >= (unsigned)N_CNT) id = 0;
                src = x + (long)id * 64 + ((p - 16) & 15) * 4;
            }
            f32x4 v = *(const f32x4*)src;
            short4v pk = { f2bf(v[0]), f2bf(v[1]), f2bf(v[2]), f2bf(v[3]) };
            *(short4v*)&s_in[el][p * 4] = pk;
        }
    };

    int tile = blockIdx.x;
    if (tile < E_TILES64) stage(tile);
    __syncthreads();

    for (; tile < E_TILES64; tile += gridDim.x) {
        const int e0 = tile * EB;

        // GEMM1: 48 MFMA/wave over 4 sub-tiles
        #pragma unroll
        for (int sub = 0; sub < 4; sub++) {
            const int row = sub * 16 + l15;
            f32x4 c0 = (f32x4){0.f, 0.f, 0.f, 0.f};
            f32x4 c1 = (f32x4){0.f, 0.f, 0.f, 0.f};
            #pragma unroll
            for (int k0 = 0; k0 < 6; k0++) {
                bf16x8 bfrag = *(const bf16x8*)&s_in[row][k0 * 32 + q * 8];
                c0 = __builtin_amdgcn_mfma_f32_16x16x32_bf16(a1[0][k0], bfrag, c0, 0, 0, 0);
                c1 = __builtin_amdgcn_mfma_f32_16x16x32_bf16(a1[1][k0], bfrag, c1, 0, 0, 0);
            }
            // bias+relu, write h (D: col=edge l15, row=hidden wave*32+t*16+q*4+r)
            short4v pk0 = { f2bf(fmaxf(c0[0] + bias1[0][0], 0.f)),
                            f2bf(fmaxf(c0[1] + bias1[0][1], 0.f)),
                            f2bf(fmaxf(c0[2] + bias1[0][2], 0.f)),
                            f2bf(fmaxf(c0[3] + bias1[0][3], 0.f)) };
            *(short4v*)&s_h[row][wave * 32 + q * 4] = pk0;
            short4v pk1 = { f2bf(fmaxf(c1[0] + bias1[1][0], 0.f)),
                            f2bf(fmaxf(c1[1] + bias1[1][1], 0.f)),
                            f2bf(fmaxf(c1[2] + bias1[1][2], 0.f)),
                            f2bf(fmaxf(c1[3] + bias1[1][3], 0.f)) };
            *(short4v*)&s_h[row][wave * 32 + 16 + q * 4] = pk1;
        }
        __syncthreads();

        // stage next tile (s_in free after GEMM1's barrier) overlapped with GEMM2
        const int nxt = tile + gridDim.x;
        if (nxt < E_TILES64) stage(nxt);

        // GEMM2: 16 MFMA/wave over 4 sub-tiles + eout store
        #pragma unroll
        for (int sub = 0; sub < 4; sub++) {
            const int row = sub * 16 + l15;
            f32x4 c2 = (f32x4){0.f, 0.f, 0.f, 0.f};
            #pragma unroll
            for (int k0 = 0; k0 < 4; k0++) {
                bf16x8 bfrag = *(const bf16x8*)&s_h[row][k0 * 32 + q * 8];
                c2 = __builtin_amdgcn_mfma_f32_16x16x32_bf16(a2[k0], bfrag, c2, 0, 0, 0);
            }
            f32x4 out;
            out[0] = c2[0] + bias2[0];
            out[1] = c2[1] + bias2[1];
            out[2] = c2[2] + bias2[2];
            out[3] = c2[3] + bias2[3];
            *(f32x4*)&eout[(long)(e0 + row) * 64 + wave * 16 + q * 4] = out;
        }
        __syncthreads();   // protect s_in (stage writes) and s_h before next iter
    }
}

// ---------------- node kernel: CSR gather-sum + MLP ----------------
// One 16-node tile per block (grid = N_TILES) for max resident waves.
__launch_bounds__(256, 4)
__global__ void node_kernel(const float* __restrict__ x,
                            const float* __restrict__ eout,
                            const int* __restrict__ offsets,
                            const int* __restrict__ counts,
                            const int* __restrict__ edge_ids,
                            const float* __restrict__ w1, const float* __restrict__ b1,
                            const float* __restrict__ w2, const float* __restrict__ b2,
                            float* __restrict__ xout) {
    __shared__ short s_in[16][136];
    __shared__ short s_h[16][136];

    const int tid  = threadIdx.x;
    const int wave = tid >> 6;
    const int l15  = tid & 15;
    const int q    = (tid & 63) >> 4;

    const int tile = blockIdx.x;
    if (tile >= N_TILES) return;
    const int n0 = tile * 16;

    bf16x8 a1[2][4];
    #pragma unroll
    for (int t = 0; t < 2; t++)
        #pragma unroll
        for (int k0 = 0; k0 < 4; k0++)
            #pragma unroll
            for (int j = 0; j < 8; j++)
                a1[t][k0][j] = f2bf(w1[(k0 * 32 + q * 8 + j) * 128 + (wave * 32 + t * 16 + l15)]);
    bf16x8 a2[4];
    #pragma unroll
    for (int k0 = 0; k0 < 4; k0++)
        #pragma unroll
        for (int j = 0; j < 8; j++)
            a2[k0][j] = f2bf(w2[(k0 * 32 + q * 8 + j) * 64 + (wave * 16 + l15)]);
    f32x4 bias1[2];
    #pragma unroll
    for (int t = 0; t < 2; t++)
        #pragma unroll
        for (int r = 0; r < 4; r++)
            bias1[t][r] = b1[wave * 32 + t * 16 + q * 4 + r];
    f32x4 bias2;
    #pragma unroll
    for (int r = 0; r < 4; r++) bias2[r] = b2[wave * 16 + q * 4 + r];

    const int gel = tid >> 4;   // node-in-tile this thread gathers for
    const int gc  = tid & 15;   // float4 chunk (0..15) of the 64-float row
    const int n   = n0 + gel;

    // stage x[n] -> s_in[:, 0:64]
    {
        f32x4 v = *(const f32x4*)(x + (long)n * 64 + gc * 4);
        short4v pk = { f2bf(v[0]), f2bf(v[1]), f2bf(v[2]), f2bf(v[3]) };
        *(short4v*)&s_in[gel][gc * 4] = pk;
    }

    // gather-sum messages[n] -> s_in[:, 64:128]
    {
        int beg = offsets[n];
        int deg = counts[n];
        f32x4 acc = (f32x4){0.f, 0.f, 0.f, 0.f};
        int j = 0;
        for (; j + 4 <= deg; j += 4) {
            int e0i = edge_ids[beg + j + 0];
            int e1i = edge_ids[beg + j + 1];
            int e2i = edge_ids[beg + j + 2];
            int e3i = edge_ids[beg + j + 3];
            f32x4 v0 = *(const f32x4*)(eout + (long)e0i * 64 + gc * 4);
            f32x4 v1 = *(const f32x4*)(eout + (long)e1i * 64 + gc * 4);
            f32x4 v2 = *(const f32x4*)(eout + (long)e2i * 64 + gc * 4);
            f32x4 v3 = *(const f32x4*)(eout + (long)e3i * 64 + gc * 4);
            #pragma unroll
            for (int r = 0; r < 4; r++) acc[r] += v0[r] + v1[r] + v2[r] + v3[r];
        }
        for (; j < deg; j++) {
            int ei = edge_ids[beg + j];
            f32x4 v = *(const f32x4*)(eout + (long)ei * 64 + gc * 4);
            #pragma unroll
            for (int r = 0; r < 4; r++) acc[r] += v[r];
        }
        short4v pk = { f2bf(acc[0]), f2bf(acc[1]), f2bf(acc[2]), f2bf(acc[3]) };
        *(short4v*)&s_in[gel][64 + gc * 4] = pk;
    }
    __syncthreads();

    f32x4 acc1[2];
    acc1[0] = (f32x4){0.f, 0.f, 0.f, 0.f};
    acc1[1] = (f32x4){0.f, 0.f, 0.f, 0.f};
    #pragma unroll
    for (int k0 = 0; k0 < 4; k0++) {
        bf16x8 bfrag = *(const bf16x8*)&s_in[l15][k0 * 32 + q * 8];
        acc1[0] = __builtin_amdgcn_mfma_f32_16x16x32_bf16(a1[0][k0], bfrag, acc1[0], 0, 0, 0);
        acc1[1] = __builtin_amdgcn_mfma_f32_16x16x32_bf16(a1[1][k0], bfrag, acc1[1], 0, 0, 0);
    }
    #pragma unroll
    for (int t = 0; t < 2; t++) {
        int hid = wave * 32 + t * 16 + q * 4;
        short4v pk = { f2bf(fmaxf(acc1[t][0] + bias1[t][0], 0.f)),
                       f2bf(fmaxf(acc1[t][1] + bias1[t][1], 0.f)),
                       f2bf(fmaxf(acc1[t][2] + bias1[t][2], 0.f)),
                       f2bf(fmaxf(acc1[t][3] + bias1[t][3], 0.f)) };
        *(short4v*)&s_h[l15][hid] = pk;
    }
    __syncthreads();

    f32x4 acc2 = (f32x4){0.f, 0.f, 0.f, 0.f};
    #pragma unroll
    for (int k0 = 0; k0 < 4; k0++) {
        bf16x8 bfrag = *(const bf16x8*)&s_h[l15][k0 * 32 + q * 8];
        acc2 = __builtin_amdgcn_mfma_f32_16x16x32_bf16(a2[k0], bfrag, acc2, 0, 0, 0);
    }
    f32x4 out;
    out[0] = acc2[0] + bias2[0];
    out[1] = acc2[1] + bias2[1];
    out[2] = acc2[2] + bias2[2];
    out[3] = acc2[3] + bias2[3];
    *(f32x4*)&xout[(long)(n0 + l15) * 64 + wave * 16 + q * 4] = out;
}

extern "C" void kernel_launch(void* const* d_in, const int* in_sizes, int n_in,
                              void* d_out, int out_size, void* d_ws, size_t ws_size,
                              hipStream_t stream) {
    const float* x     = (const float*)d_in[0];
    const int*   eidx  = (const int*)d_in[1];
    const float* eattr = (const float*)d_in[2];
    const float* eW1   = (const float*)d_in[3];
    const float* eb1   = (const float*)d_in[4];
    const float* eW2   = (const float*)d_in[5];
    const float* eb2   = (const float*)d_in[6];
    const float* nW1   = (const float*)d_in[7];
    const float* nb1   = (const float*)d_in[8];
    const float* nW2   = (const float*)d_in[9];
    const float* nb2   = (const float*)d_in[10];

    char* ws = (char*)d_ws;
    int* counts   = (int*)(ws + WS_COUNTS);
    int* offsets  = (int*)(ws + WS_OFFSETS);
    int* cursor   = (int*)(ws + WS_CURSOR);
    int* bsum     = (int*)(ws + WS_BSUM);
    int* edge_ids = (int*)(ws + WS_EIDS);

    float* xout = (float*)d_out;
    float* eout = xout + (long)N_CNT * 64;

    hipMemsetAsync(counts, 0, 204800, stream);
    hist_kernel<<<1024, 256, 0, stream>>>(eidx, counts);
    scan_block_sums<<<SCAN_BLOCKS, 256, 0, stream>>>(counts, bsum);
    scan_top<<<1, 256, 0, stream>>>(bsum);
    scan_within<<<SCAN_BLOCKS, 256, 0, stream>>>(counts, bsum, offsets, cursor);
    scatter_kernel<<<1024, 256, 0, stream>>>(eidx, cursor, edge_ids);

    edge_kernel<<<2048, 256, 0, stream>>>(x, eidx, eattr, eW1, eb1, eW2, eb2, eout);
    node_kernel<<<N_TILES, 256, 0, stream>>>(x, eout, offsets, counts, edge_ids,
                                             nW1, nb1, nW2, nb2, xout);
}

// Round 3
// 724.222 us; speedup vs baseline: 1.0438x; 1.0438x over previous
//
#include <hip/hip_runtime.h>
#include <hip/hip_bf16.h>

#define E_CNT 800000
#define N_CNT 50000
#define EB 64                      // edges per block-iteration (4 sub-tiles of 16)
#define E_TILES64 (E_CNT / EB)     // 12500
#define N_TILES (N_CNT / 16)       // 3125
#define SCAN_BLOCKS 196            // ceil(50000 / 256)

// ---- workspace layout (bytes) ----
#define WS_COUNTS  0
#define WS_OFFSETS 204800
#define WS_CURSOR  409600
#define WS_BSUM    614400
#define WS_EIDS    615424

typedef __attribute__((ext_vector_type(8))) short bf16x8;   // MFMA A/B frag (8 bf16)
typedef __attribute__((ext_vector_type(4))) short short4v;  // 4 bf16 packed store
typedef __attribute__((ext_vector_type(4))) float f32x4;    // MFMA C/D frag / float4

static __device__ __forceinline__ short f2bf(float v) {
    union { __hip_bfloat16 b; short u; } cv;
    cv.b = __float2bfloat16(v);
    return cv.u;
}

// ---------------- CSR build: histogram -> scan -> scatter ----------------

__global__ void hist_kernel(const int* __restrict__ eidx, int* __restrict__ counts) {
    int stride = gridDim.x * blockDim.x;
    for (int i = blockIdx.x * blockDim.x + threadIdx.x; i < E_CNT; i += stride) {
        int d = eidx[E_CNT + i];
        if ((unsigned)d >= (unsigned)N_CNT) d = 0;
        atomicAdd(&counts[d], 1);
    }
}

__global__ void scan_block_sums(const int* __restrict__ counts, int* __restrict__ bsum) {
    __shared__ int s[256];
    int t = threadIdx.x;
    int i = blockIdx.x * 256 + t;
    s[t] = (i < N_CNT) ? counts[i] : 0;
    __syncthreads();
    #pragma unroll
    for (int off = 128; off; off >>= 1) {
        if (t < off) s[t] += s[t + off];
        __syncthreads();
    }
    if (t == 0) bsum[blockIdx.x] = s[0];
}

__global__ void scan_top(int* __restrict__ bsum) {
    __shared__ int s[256];
    int t = threadIdx.x;
    int mine = (t < SCAN_BLOCKS) ? bsum[t] : 0;
    s[t] = mine;
    __syncthreads();
    #pragma unroll
    for (int off = 1; off < 256; off <<= 1) {
        int v = (t >= off) ? s[t - off] : 0;
        __syncthreads();
        s[t] += v;
        __syncthreads();
    }
    if (t < SCAN_BLOCKS) bsum[t] = s[t] - mine;   // inclusive -> exclusive
}

__global__ void scan_within(const int* __restrict__ counts, const int* __restrict__ bsum,
                            int* __restrict__ offsets, int* __restrict__ cursor) {
    __shared__ int s[256];
    int t = threadIdx.x;
    int i = blockIdx.x * 256 + t;
    int mine = (i < N_CNT) ? counts[i] : 0;
    s[t] = mine;
    __syncthreads();
    #pragma unroll
    for (int off = 1; off < 256; off <<= 1) {
        int v = (t >= off) ? s[t - off] : 0;
        __syncthreads();
        s[t] += v;
        __syncthreads();
    }
    if (i < N_CNT) {
        int o = bsum[blockIdx.x] + s[t] - mine;   // exclusive prefix
        offsets[i] = o;
        cursor[i]  = o;
    }
}

__global__ void scatter_kernel(const int* __restrict__ eidx, int* __restrict__ cursor,
                               int* __restrict__ edge_ids) {
    int stride = gridDim.x * blockDim.x;
    for (int i = blockIdx.x * blockDim.x + threadIdx.x; i < E_CNT; i += stride) {
        int d = eidx[E_CNT + i];
        if ((unsigned)d >= (unsigned)N_CNT) d = 0;
        int pos = atomicAdd(&cursor[d], 1);
        edge_ids[pos] = i;
    }
}

// ---------------- edge kernel: two-phase branchless staging ----------------
// 4 waves cooperate on a 64-edge tile. Swapped-operand MFMA:
// GEMM1 h^T = W1^T(A,regs) * edge_in^T(B,LDS), K=192;
// GEMM2 out^T = W2^T(A,regs) * h^T(B,LDS), K=128.
// Per iter: load_ids(next) | GEMM1 | barrier | stage_data(next) + GEMM2 | barrier.
// KEY: id loads are a separate independent batch (one latency), data loads use a
// branchless pointer select (no exec-mask divergence -> no per-iter vmcnt drains).
__launch_bounds__(256, 3)
__global__ void edge_kernel(const float* __restrict__ x,
                            const int* __restrict__ eidx,
                            const float* __restrict__ eattr,
                            const float* __restrict__ w1, const float* __restrict__ b1,
                            const float* __restrict__ w2, const float* __restrict__ b2,
                            float* __restrict__ eout) {
    __shared__ short s_in[EB][200];   // edge_in rows bf16 (192 + 8 pad)  25.6 KB
    __shared__ short s_h[EB][136];    // h rows bf16 (128 + 8 pad)        17.4 KB

    const int tid  = threadIdx.x;
    const int wave = tid >> 6;
    const int l15  = tid & 15;
    const int q    = (tid & 63) >> 4;

    // ---- weight fragments -> registers (once per block), fp32 -> bf16 ----
    bf16x8 a1[2][6];
    #pragma unroll
    for (int t = 0; t < 2; t++)
        #pragma unroll
        for (int k0 = 0; k0 < 6; k0++)
            #pragma unroll
            for (int j = 0; j < 8; j++)
                a1[t][k0][j] = f2bf(w1[(k0 * 32 + q * 8 + j) * 128 + (wave * 32 + t * 16 + l15)]);
    bf16x8 a2[4];
    #pragma unroll
    for (int k0 = 0; k0 < 4; k0++)
        #pragma unroll
        for (int j = 0; j < 8; j++)
            a2[k0][j] = f2bf(w2[(k0 * 32 + q * 8 + j) * 64 + (wave * 16 + l15)]);
    f32x4 bias1[2];
    #pragma unroll
    for (int t = 0; t < 2; t++)
        #pragma unroll
        for (int r = 0; r < 4; r++)
            bias1[t][r] = b1[wave * 32 + t * 16 + q * 4 + r];
    f32x4 bias2;
    #pragma unroll
    for (int r = 0; r < 4; r++) bias2[r] = b2[wave * 16 + q * 4 + r];

    // phase 1: all id loads for a tile, independent (one latency, overlappable)
    auto load_ids = [&](int tile, int* ids) {
        const int e0 = tile * EB;
        #pragma unroll
        for (int i = 0; i < 12; i++) {
            int c  = tid + 256 * i;
            int el = c / 48, p = c - el * 48;
            ids[i] = eidx[(p >= 32 ? E_CNT : 0) + e0 + el];  // branchless offset
        }
    };
    // phase 2: all data loads, branchless address select, all independent
    auto stage_data = [&](int tile, const int* ids) {
        const int e0 = tile * EB;
        #pragma unroll
        for (int i = 0; i < 12; i++) {
            int c  = tid + 256 * i;
            int el = c / 48, p = c - el * 48;
            int id = ids[i];
            if ((unsigned)id >= (unsigned)N_CNT) id = 0;
            const float* src = (p < 16)
                ? eattr + (long)(e0 + el) * 64 + p * 4
                : x + (long)id * 64 + ((p - 16) & 15) * 4;
            f32x4 v = *(const f32x4*)src;
            short4v pk = { f2bf(v[0]), f2bf(v[1]), f2bf(v[2]), f2bf(v[3]) };
            *(short4v*)&s_in[el][p * 4] = pk;
        }
    };

    int tile = blockIdx.x;
    if (tile < E_TILES64) {
        int ids0[12];
        load_ids(tile, ids0);
        stage_data(tile, ids0);
    }
    __syncthreads();

    for (; tile < E_TILES64; tile += gridDim.x) {
        const int e0  = tile * EB;
        const int nxt = tile + gridDim.x;
        const int pf  = (nxt < E_TILES64) ? nxt : tile;  // clamp: re-stage self on last iter

        int ids[12];
        load_ids(pf, ids);          // id latency hidden under GEMM1

        // GEMM1: 48 MFMA/wave over 4 sub-tiles
        #pragma unroll
        for (int sub = 0; sub < 4; sub++) {
            const int row = sub * 16 + l15;
            f32x4 c0 = (f32x4){0.f, 0.f, 0.f, 0.f};
            f32x4 c1 = (f32x4){0.f, 0.f, 0.f, 0.f};
            #pragma unroll
            for (int k0 = 0; k0 < 6; k0++) {
                bf16x8 bfrag = *(const bf16x8*)&s_in[row][k0 * 32 + q * 8];
                c0 = __builtin_amdgcn_mfma_f32_16x16x32_bf16(a1[0][k0], bfrag, c0, 0, 0, 0);
                c1 = __builtin_amdgcn_mfma_f32_16x16x32_bf16(a1[1][k0], bfrag, c1, 0, 0, 0);
            }
            short4v pk0 = { f2bf(fmaxf(c0[0] + bias1[0][0], 0.f)),
                            f2bf(fmaxf(c0[1] + bias1[0][1], 0.f)),
                            f2bf(fmaxf(c0[2] + bias1[0][2], 0.f)),
                            f2bf(fmaxf(c0[3] + bias1[0][3], 0.f)) };
            *(short4v*)&s_h[row][wave * 32 + q * 4] = pk0;
            short4v pk1 = { f2bf(fmaxf(c1[0] + bias1[1][0], 0.f)),
                            f2bf(fmaxf(c1[1] + bias1[1][1], 0.f)),
                            f2bf(fmaxf(c1[2] + bias1[1][2], 0.f)),
                            f2bf(fmaxf(c1[3] + bias1[1][3], 0.f)) };
            *(short4v*)&s_h[row][wave * 32 + 16 + q * 4] = pk1;
        }
        __syncthreads();   // s_h ready, s_in free

        stage_data(pf, ids);   // data loads overlap GEMM2 below

        // GEMM2: 16 MFMA/wave over 4 sub-tiles + eout store
        #pragma unroll
        for (int sub = 0; sub < 4; sub++) {
            const int row = sub * 16 + l15;
            f32x4 c2 = (f32x4){0.f, 0.f, 0.f, 0.f};
            #pragma unroll
            for (int k0 = 0; k0 < 4; k0++) {
                bf16x8 bfrag = *(const bf16x8*)&s_h[row][k0 * 32 + q * 8];
                c2 = __builtin_amdgcn_mfma_f32_16x16x32_bf16(a2[k0], bfrag, c2, 0, 0, 0);
            }
            f32x4 out;
            out[0] = c2[0] + bias2[0];
            out[1] = c2[1] + bias2[1];
            out[2] = c2[2] + bias2[2];
            out[3] = c2[3] + bias2[3];
            *(f32x4*)&eout[(long)(e0 + row) * 64 + wave * 16 + q * 4] = out;
        }
        __syncthreads();   // stage_data writes + s_h reads complete
    }
}

// ---------------- node kernel: CSR gather-sum + MLP ----------------
// Grid-stride (amortize weight preload); gather in two-phase batches of 8
// (8 independent id loads, then 8 independent data loads, branchless tail).
__launch_bounds__(256, 4)
__global__ void node_kernel(const float* __restrict__ x,
                            const float* __restrict__ eout,
                            const int* __restrict__ offsets,
                            const int* __restrict__ counts,
                            const int* __restrict__ edge_ids,
                            const float* __restrict__ w1, const float* __restrict__ b1,
                            const float* __restrict__ w2, const float* __restrict__ b2,
                            float* __restrict__ xout) {
    __shared__ short s_in[16][136];
    __shared__ short s_h[16][136];

    const int tid  = threadIdx.x;
    const int wave = tid >> 6;
    const int l15  = tid & 15;
    const int q    = (tid & 63) >> 4;

    bf16x8 a1[2][4];
    #pragma unroll
    for (int t = 0; t < 2; t++)
        #pragma unroll
        for (int k0 = 0; k0 < 4; k0++)
            #pragma unroll
            for (int j = 0; j < 8; j++)
                a1[t][k0][j] = f2bf(w1[(k0 * 32 + q * 8 + j) * 128 + (wave * 32 + t * 16 + l15)]);
    bf16x8 a2[4];
    #pragma unroll
    for (int k0 = 0; k0 < 4; k0++)
        #pragma unroll
        for (int j = 0; j < 8; j++)
            a2[k0][j] = f2bf(w2[(k0 * 32 + q * 8 + j) * 64 + (wave * 16 + l15)]);
    f32x4 bias1[2];
    #pragma unroll
    for (int t = 0; t < 2; t++)
        #pragma unroll
        for (int r = 0; r < 4; r++)
            bias1[t][r] = b1[wave * 32 + t * 16 + q * 4 + r];
    f32x4 bias2;
    #pragma unroll
    for (int r = 0; r < 4; r++) bias2[r] = b2[wave * 16 + q * 4 + r];

    const int gel = tid >> 4;   // node-in-tile this thread gathers for
    const int gc  = tid & 15;   // float4 chunk (0..15) of the 64-float row

    for (int tile = blockIdx.x; tile < N_TILES; tile += gridDim.x) {
        const int n0 = tile * 16;
        const int n  = n0 + gel;

        // stage x[n] -> s_in[:, 0:64]
        {
            f32x4 v = *(const f32x4*)(x + (long)n * 64 + gc * 4);
            short4v pk = { f2bf(v[0]), f2bf(v[1]), f2bf(v[2]), f2bf(v[3]) };
            *(short4v*)&s_in[gel][gc * 4] = pk;
        }

        // gather-sum messages[n] -> s_in[:, 64:128]
        {
            int beg = offsets[n];
            int deg = counts[n];
            f32x4 acc = (f32x4){0.f, 0.f, 0.f, 0.f};
            for (int j = 0; j < deg; j += 8) {
                // phase 1: 8 independent id loads (clamped -> always valid)
                int ids[8];
                #pragma unroll
                for (int u = 0; u < 8; u++) {
                    int idx = (j + u < deg) ? (beg + j + u) : beg;
                    ids[u] = edge_ids[idx];
                }
                // phase 2: 8 independent data loads, 0/1-weighted accumulate
                #pragma unroll
                for (int u = 0; u < 8; u++) {
                    f32x4 v = *(const f32x4*)(eout + (long)ids[u] * 64 + gc * 4);
                    float w = (j + u < deg) ? 1.f : 0.f;
                    #pragma unroll
                    for (int r = 0; r < 4; r++) acc[r] += v[r] * w;
                }
            }
            short4v pk = { f2bf(acc[0]), f2bf(acc[1]), f2bf(acc[2]), f2bf(acc[3]) };
            *(short4v*)&s_in[gel][64 + gc * 4] = pk;
        }
        __syncthreads();

        f32x4 acc1[2];
        acc1[0] = (f32x4){0.f, 0.f, 0.f, 0.f};
        acc1[1] = (f32x4){0.f, 0.f, 0.f, 0.f};
        #pragma unroll
        for (int k0 = 0; k0 < 4; k0++) {
            bf16x8 bfrag = *(const bf16x8*)&s_in[l15][k0 * 32 + q * 8];
            acc1[0] = __builtin_amdgcn_mfma_f32_16x16x32_bf16(a1[0][k0], bfrag, acc1[0], 0, 0, 0);
            acc1[1] = __builtin_amdgcn_mfma_f32_16x16x32_bf16(a1[1][k0], bfrag, acc1[1], 0, 0, 0);
        }
        #pragma unroll
        for (int t = 0; t < 2; t++) {
            int hid = wave * 32 + t * 16 + q * 4;
            short4v pk = { f2bf(fmaxf(acc1[t][0] + bias1[t][0], 0.f)),
                           f2bf(fmaxf(acc1[t][1] + bias1[t][1], 0.f)),
                           f2bf(fmaxf(acc1[t][2] + bias1[t][2], 0.f)),
                           f2bf(fmaxf(acc1[t][3] + bias1[t][3], 0.f)) };
            *(short4v*)&s_h[l15][hid] = pk;
        }
        __syncthreads();

        f32x4 acc2 = (f32x4){0.f, 0.f, 0.f, 0.f};
        #pragma unroll
        for (int k0 = 0; k0 < 4; k0++) {
            bf16x8 bfrag = *(const bf16x8*)&s_h[l15][k0 * 32 + q * 8];
            acc2 = __builtin_amdgcn_mfma_f32_16x16x32_bf16(a2[k0], bfrag, acc2, 0, 0, 0);
        }
        f32x4 out;
        out[0] = acc2[0] + bias2[0];
        out[1] = acc2[1] + bias2[1];
        out[2] = acc2[2] + bias2[2];
        out[3] = acc2[3] + bias2[3];
        *(f32x4*)&xout[(long)(n0 + l15) * 64 + wave * 16 + q * 4] = out;
        __syncthreads();
    }
}

extern "C" void kernel_launch(void* const* d_in, const int* in_sizes, int n_in,
                              void* d_out, int out_size, void* d_ws, size_t ws_size,
                              hipStream_t stream) {
    const float* x     = (const float*)d_in[0];
    const int*   eidx  = (const int*)d_in[1];
    const float* eattr = (const float*)d_in[2];
    const float* eW1   = (const float*)d_in[3];
    const float* eb1   = (const float*)d_in[4];
    const float* eW2   = (const float*)d_in[5];
    const float* eb2   = (const float*)d_in[6];
    const float* nW1   = (const float*)d_in[7];
    const float* nb1   = (const float*)d_in[8];
    const float* nW2   = (const float*)d_in[9];
    const float* nb2   = (const float*)d_in[10];

    char* ws = (char*)d_ws;
    int* counts   = (int*)(ws + WS_COUNTS);
    int* offsets  = (int*)(ws + WS_OFFSETS);
    int* cursor   = (int*)(ws + WS_CURSOR);
    int* bsum     = (int*)(ws + WS_BSUM);
    int* edge_ids = (int*)(ws + WS_EIDS);

    float* xout = (float*)d_out;
    float* eout = xout + (long)N_CNT * 64;

    hipMemsetAsync(counts, 0, 204800, stream);
    hist_kernel<<<1024, 256, 0, stream>>>(eidx, counts);
    scan_block_sums<<<SCAN_BLOCKS, 256, 0, stream>>>(counts, bsum);
    scan_top<<<1, 256, 0, stream>>>(bsum);
    scan_within<<<SCAN_BLOCKS, 256, 0, stream>>>(counts, bsum, offsets, cursor);
    scatter_kernel<<<1024, 256, 0, stream>>>(eidx, cursor, edge_ids);

    edge_kernel<<<2048, 256, 0, stream>>>(x, eidx, eattr, eW1, eb1, eW2, eb2, eout);
    node_kernel<<<1024, 256, 0, stream>>>(x, eout, offsets, counts, edge_ids,
                                          nW1, nb1, nW2, nb2, xout);
}

// Round 4
// 638.763 us; speedup vs baseline: 1.1834x; 1.1338x over previous
//
#include <hip/hip_runtime.h>
#include <hip/hip_bf16.h>

#define E_CNT 800000
#define N_CNT 50000
#define E_TILES (E_CNT / 16)       // 50000 16-edge tiles
#define N_TILES (N_CNT / 16)       // 3125
#define SCAN_BLOCKS 196            // ceil(50000 / 256)

// ---- workspace layout (bytes) ----
#define WS_COUNTS  0
#define WS_OFFSETS 204800
#define WS_CURSOR  409600
#define WS_BSUM    614400
#define WS_EIDS    615424

typedef __attribute__((ext_vector_type(8))) short bf16x8;   // MFMA A/B frag (8 bf16)
typedef __attribute__((ext_vector_type(4))) short short4v;  // 4 bf16 packed store
typedef __attribute__((ext_vector_type(4))) float f32x4;    // MFMA C/D frag / float4

static __device__ __forceinline__ short f2bf(float v) {
    union { __hip_bfloat16 b; short u; } cv;
    cv.b = __float2bfloat16(v);
    return cv.u;
}

// async global->LDS DMA, 16B per lane, lands at lds_base + lane*16 (wave-uniform base)
static __device__ __forceinline__ void gload_lds16(const float* g, float* l) {
    __builtin_amdgcn_global_load_lds(
        (const __attribute__((address_space(1))) void*)g,
        (__attribute__((address_space(3))) void*)l, 16, 0, 0);
}

// ---------------- CSR build: histogram -> scan -> scatter ----------------

__global__ void hist_kernel(const int* __restrict__ eidx, int* __restrict__ counts) {
    int stride = gridDim.x * blockDim.x;
    for (int i = blockIdx.x * blockDim.x + threadIdx.x; i < E_CNT; i += stride) {
        int d = eidx[E_CNT + i];
        if ((unsigned)d >= (unsigned)N_CNT) d = 0;
        atomicAdd(&counts[d], 1);
    }
}

__global__ void scan_block_sums(const int* __restrict__ counts, int* __restrict__ bsum) {
    __shared__ int s[256];
    int t = threadIdx.x;
    int i = blockIdx.x * 256 + t;
    s[t] = (i < N_CNT) ? counts[i] : 0;
    __syncthreads();
    #pragma unroll
    for (int off = 128; off; off >>= 1) {
        if (t < off) s[t] += s[t + off];
        __syncthreads();
    }
    if (t == 0) bsum[blockIdx.x] = s[0];
}

__global__ void scan_top(int* __restrict__ bsum) {
    __shared__ int s[256];
    int t = threadIdx.x;
    int mine = (t < SCAN_BLOCKS) ? bsum[t] : 0;
    s[t] = mine;
    __syncthreads();
    #pragma unroll
    for (int off = 1; off < 256; off <<= 1) {
        int v = (t >= off) ? s[t - off] : 0;
        __syncthreads();
        s[t] += v;
        __syncthreads();
    }
    if (t < SCAN_BLOCKS) bsum[t] = s[t] - mine;   // inclusive -> exclusive
}

__global__ void scan_within(const int* __restrict__ counts, const int* __restrict__ bsum,
                            int* __restrict__ offsets, int* __restrict__ cursor) {
    __shared__ int s[256];
    int t = threadIdx.x;
    int i = blockIdx.x * 256 + t;
    int mine = (i < N_CNT) ? counts[i] : 0;
    s[t] = mine;
    __syncthreads();
    #pragma unroll
    for (int off = 1; off < 256; off <<= 1) {
        int v = (t >= off) ? s[t - off] : 0;
        __syncthreads();
        s[t] += v;
        __syncthreads();
    }
    if (i < N_CNT) {
        int o = bsum[blockIdx.x] + s[t] - mine;   // exclusive prefix
        offsets[i] = o;
        cursor[i]  = o;
    }
}

__global__ void scatter_kernel(const int* __restrict__ eidx, int* __restrict__ cursor,
                               int* __restrict__ edge_ids) {
    int stride = gridDim.x * blockDim.x;
    for (int i = blockIdx.x * blockDim.x + threadIdx.x; i < E_CNT; i += stride) {
        int d = eidx[E_CNT + i];
        if ((unsigned)d >= (unsigned)N_CNT) d = 0;
        int pos = atomicAdd(&cursor[d], 1);
        edge_ids[pos] = i;
    }
}

// ---------------- edge kernel: DMA-staged (global_load_lds), double-buffered ----------------
// 16-edge tiles, 4 waves/block. s_in holds RAW FP32 edge_in in chunk-major layout:
//   float index of (row, float-chunk p, j) = (p*16 + row)*4 + j   (p in [0,48), row in [0,16))
// Staging is 12 x 1KB DMA wave-instructions per tile (3 per wave), zero staging VGPRs.
// GEMM1 converts fp32->bf16 at fragment-read time.
// Swapped-operand MFMA: GEMM1 h^T = W1^T(A,regs) * edge_in^T(B,LDS), K=192;
// GEMM2 out^T = W2^T(A,regs) * h^T(B,LDS), K=128.
__launch_bounds__(256, 4)
__global__ void edge_kernel(const float* __restrict__ x,
                            const int* __restrict__ eidx,
                            const float* __restrict__ eattr,
                            const float* __restrict__ w1, const float* __restrict__ b1,
                            const float* __restrict__ w2, const float* __restrict__ b2,
                            float* __restrict__ eout) {
    __shared__ float s_in[2][3072];   // 2 x 12288B fp32 tile buffers (chunk-major)
    __shared__ short s_h[16][136];    // h rows bf16 (128 + 8 pad)

    const int tid  = threadIdx.x;
    const int wave = tid >> 6;
    const int lane = tid & 63;
    const int l15  = tid & 15;
    const int q    = (tid & 63) >> 4;

    // ---- weight fragments -> registers (once per block), fp32 -> bf16 ----
    bf16x8 a1[2][6];
    #pragma unroll
    for (int t = 0; t < 2; t++)
        #pragma unroll
        for (int k0 = 0; k0 < 6; k0++)
            #pragma unroll
            for (int j = 0; j < 8; j++)
                a1[t][k0][j] = f2bf(w1[(k0 * 32 + q * 8 + j) * 128 + (wave * 32 + t * 16 + l15)]);
    bf16x8 a2[4];
    #pragma unroll
    for (int k0 = 0; k0 < 4; k0++)
        #pragma unroll
        for (int j = 0; j < 8; j++)
            a2[k0][j] = f2bf(w2[(k0 * 32 + q * 8 + j) * 64 + (wave * 16 + l15)]);
    f32x4 bias1[2];
    #pragma unroll
    for (int t = 0; t < 2; t++)
        #pragma unroll
        for (int r = 0; r < 4; r++)
            bias1[t][r] = b1[wave * 32 + t * 16 + q * 4 + r];
    f32x4 bias2;
    #pragma unroll
    for (int r = 0; r < 4; r++) bias2[r] = b2[wave * 16 + q * 4 + r];

    // this lane's 3 staging chunks: k = (wave*3+i)*64 + lane; p = k>>4 (float4 chunk), row = k&15
    const int kbase = wave * 192 + lane;

    auto load_ids = [&](int tile, int* ids) {
        const int e0 = tile * 16;
        #pragma unroll
        for (int i = 0; i < 3; i++) {
            int k = kbase + i * 64;
            int p = k >> 4, row = k & 15;
            ids[i] = eidx[(p >= 32 ? E_CNT : 0) + e0 + row];   // unused for p<16, still valid addr
        }
    };
    auto stage = [&](int tile, int buf, const int* ids) {
        const int e0 = tile * 16;
        #pragma unroll
        for (int i = 0; i < 3; i++) {
            int k = kbase + i * 64;
            int p = k >> 4, row = k & 15;
            int id = ids[i];
            if ((unsigned)id >= (unsigned)N_CNT) id = 0;
            const float* g = (p < 16)
                ? eattr + (long)(e0 + row) * 64 + p * 4
                : x + (long)id * 64 + ((p - 16) & 15) * 4;
            // wave-uniform LDS base; HW scatters lane L to base + L*16
            gload_lds16(g, &s_in[buf][(wave * 3 + i) * 256]);
        }
    };

    int tile = blockIdx.x;                 // grid (2048) << E_TILES, always valid
    int idsB[3] = {0, 0, 0};
    {
        int idsA[3];
        load_ids(tile, idsA);
        stage(tile, 0, idsA);
        int nxt = tile + (int)gridDim.x;
        if (nxt < E_TILES) load_ids(nxt, idsB);
    }
    __syncthreads();                        // drains DMA: buf0 staged
    int cur = 0;

    for (; tile < E_TILES; tile += gridDim.x) {
        const int e0  = tile * 16;
        const int nxt = tile + (int)gridDim.x;
        const int nn  = nxt + (int)gridDim.x;

        if (nxt < E_TILES) stage(nxt, cur ^ 1, idsB);   // DMA next tile, no regs held
        if (nn  < E_TILES) load_ids(nn, idsB);          // ids two tiles ahead

        // GEMM1: 12 MFMA/wave, fp32 LDS reads + cvt to bf16 frags
        f32x4 acc1[2];
        acc1[0] = (f32x4){0.f, 0.f, 0.f, 0.f};
        acc1[1] = (f32x4){0.f, 0.f, 0.f, 0.f};
        #pragma unroll
        for (int k0 = 0; k0 < 6; k0++) {
            const int p0 = k0 * 8 + q * 2;
            f32x4 u0 = *(const f32x4*)&s_in[cur][(p0 * 16 + l15) * 4];
            f32x4 u1 = *(const f32x4*)&s_in[cur][((p0 + 1) * 16 + l15) * 4];
            bf16x8 bfrag;
            bfrag[0] = f2bf(u0[0]); bfrag[1] = f2bf(u0[1]);
            bfrag[2] = f2bf(u0[2]); bfrag[3] = f2bf(u0[3]);
            bfrag[4] = f2bf(u1[0]); bfrag[5] = f2bf(u1[1]);
            bfrag[6] = f2bf(u1[2]); bfrag[7] = f2bf(u1[3]);
            acc1[0] = __builtin_amdgcn_mfma_f32_16x16x32_bf16(a1[0][k0], bfrag, acc1[0], 0, 0, 0);
            acc1[1] = __builtin_amdgcn_mfma_f32_16x16x32_bf16(a1[1][k0], bfrag, acc1[1], 0, 0, 0);
        }
        // bias+relu, write h (D: col=edge l15, row=hidden wave*32+t*16+q*4+r)
        #pragma unroll
        for (int t = 0; t < 2; t++) {
            int hid = wave * 32 + t * 16 + q * 4;
            short4v pk = { f2bf(fmaxf(acc1[t][0] + bias1[t][0], 0.f)),
                           f2bf(fmaxf(acc1[t][1] + bias1[t][1], 0.f)),
                           f2bf(fmaxf(acc1[t][2] + bias1[t][2], 0.f)),
                           f2bf(fmaxf(acc1[t][3] + bias1[t][3], 0.f)) };
            *(short4v*)&s_h[l15][hid] = pk;
        }
        __syncthreads();   // s_h ready (also drains next-tile DMA; overlap = GEMM1)

        // GEMM2: 4 MFMA/wave + eout store
        f32x4 acc2 = (f32x4){0.f, 0.f, 0.f, 0.f};
        #pragma unroll
        for (int k0 = 0; k0 < 4; k0++) {
            bf16x8 bfrag = *(const bf16x8*)&s_h[l15][k0 * 32 + q * 8];
            acc2 = __builtin_amdgcn_mfma_f32_16x16x32_bf16(a2[k0], bfrag, acc2, 0, 0, 0);
        }
        f32x4 out;
        out[0] = acc2[0] + bias2[0];
        out[1] = acc2[1] + bias2[1];
        out[2] = acc2[2] + bias2[2];
        out[3] = acc2[3] + bias2[3];
        *(f32x4*)&eout[(long)(e0 + l15) * 64 + wave * 16 + q * 4] = out;
        __syncthreads();   // s_h safe to rewrite; buf[cur] safe (reads done pre-mid-barrier)
        cur ^= 1;
    }
}

// ---------------- node kernel: CSR gather-sum + MLP ----------------
// Grid-stride; gather in two-phase batches of 8 (8 independent id loads, then
// 8 independent eout-row loads, branchless 0/1-weighted tail).
__launch_bounds__(256, 4)
__global__ void node_kernel(const float* __restrict__ x,
                            const float* __restrict__ eout,
                            const int* __restrict__ offsets,
                            const int* __restrict__ counts,
                            const int* __restrict__ edge_ids,
                            const float* __restrict__ w1, const float* __restrict__ b1,
                            const float* __restrict__ w2, const float* __restrict__ b2,
                            float* __restrict__ xout) {
    __shared__ short s_in[16][136];
    __shared__ short s_h[16][136];

    const int tid  = threadIdx.x;
    const int wave = tid >> 6;
    const int l15  = tid & 15;
    const int q    = (tid & 63) >> 4;

    bf16x8 a1[2][4];
    #pragma unroll
    for (int t = 0; t < 2; t++)
        #pragma unroll
        for (int k0 = 0; k0 < 4; k0++)
            #pragma unroll
            for (int j = 0; j < 8; j++)
                a1[t][k0][j] = f2bf(w1[(k0 * 32 + q * 8 + j) * 128 + (wave * 32 + t * 16 + l15)]);
    bf16x8 a2[4];
    #pragma unroll
    for (int k0 = 0; k0 < 4; k0++)
        #pragma unroll
        for (int j = 0; j < 8; j++)
            a2[k0][j] = f2bf(w2[(k0 * 32 + q * 8 + j) * 64 + (wave * 16 + l15)]);
    f32x4 bias1[2];
    #pragma unroll
    for (int t = 0; t < 2; t++)
        #pragma unroll
        for (int r = 0; r < 4; r++)
            bias1[t][r] = b1[wave * 32 + t * 16 + q * 4 + r];
    f32x4 bias2;
    #pragma unroll
    for (int r = 0; r < 4; r++) bias2[r] = b2[wave * 16 + q * 4 + r];

    const int gel = tid >> 4;   // node-in-tile this thread gathers for
    const int gc  = tid & 15;   // float4 chunk (0..15) of the 64-float row

    for (int tile = blockIdx.x; tile < N_TILES; tile += gridDim.x) {
        const int n0 = tile * 16;
        const int n  = n0 + gel;

        // stage x[n] -> s_in[:, 0:64]
        {
            f32x4 v = *(const f32x4*)(x + (long)n * 64 + gc * 4);
            short4v pk = { f2bf(v[0]), f2bf(v[1]), f2bf(v[2]), f2bf(v[3]) };
            *(short4v*)&s_in[gel][gc * 4] = pk;
        }

        // gather-sum messages[n] -> s_in[:, 64:128]
        {
            int beg = offsets[n];
            int deg = counts[n];
            f32x4 acc = (f32x4){0.f, 0.f, 0.f, 0.f};
            for (int j = 0; j < deg; j += 8) {
                int ids[8];
                #pragma unroll
                for (int u = 0; u < 8; u++) {
                    int idx = (j + u < deg) ? (beg + j + u) : beg;
                    ids[u] = edge_ids[idx];
                }
                #pragma unroll
                for (int u = 0; u < 8; u++) {
                    f32x4 v = *(const f32x4*)(eout + (long)ids[u] * 64 + gc * 4);
                    float w = (j + u < deg) ? 1.f : 0.f;
                    #pragma unroll
                    for (int r = 0; r < 4; r++) acc[r] += v[r] * w;
                }
            }
            short4v pk = { f2bf(acc[0]), f2bf(acc[1]), f2bf(acc[2]), f2bf(acc[3]) };
            *(short4v*)&s_in[gel][64 + gc * 4] = pk;
        }
        __syncthreads();

        f32x4 acc1[2];
        acc1[0] = (f32x4){0.f, 0.f, 0.f, 0.f};
        acc1[1] = (f32x4){0.f, 0.f, 0.f, 0.f};
        #pragma unroll
        for (int k0 = 0; k0 < 4; k0++) {
            bf16x8 bfrag = *(const bf16x8*)&s_in[l15][k0 * 32 + q * 8];
            acc1[0] = __builtin_amdgcn_mfma_f32_16x16x32_bf16(a1[0][k0], bfrag, acc1[0], 0, 0, 0);
            acc1[1] = __builtin_amdgcn_mfma_f32_16x16x32_bf16(a1[1][k0], bfrag, acc1[1], 0, 0, 0);
        }
        #pragma unroll
        for (int t = 0; t < 2; t++) {
            int hid = wave * 32 + t * 16 + q * 4;
            short4v pk = { f2bf(fmaxf(acc1[t][0] + bias1[t][0], 0.f)),
                           f2bf(fmaxf(acc1[t][1] + bias1[t][1], 0.f)),
                           f2bf(fmaxf(acc1[t][2] + bias1[t][2], 0.f)),
                           f2bf(fmaxf(acc1[t][3] + bias1[t][3], 0.f)) };
            *(short4v*)&s_h[l15][hid] = pk;
        }
        __syncthreads();

        f32x4 acc2 = (f32x4){0.f, 0.f, 0.f, 0.f};
        #pragma unroll
        for (int k0 = 0; k0 < 4; k0++) {
            bf16x8 bfrag = *(const bf16x8*)&s_h[l15][k0 * 32 + q * 8];
            acc2 = __builtin_amdgcn_mfma_f32_16x16x32_bf16(a2[k0], bfrag, acc2, 0, 0, 0);
        }
        f32x4 out;
        out[0] = acc2[0] + bias2[0];
        out[1] = acc2[1] + bias2[1];
        out[2] = acc2[2] + bias2[2];
        out[3] = acc2[3] + bias2[3];
        *(f32x4*)&xout[(long)(n0 + l15) * 64 + wave * 16 + q * 4] = out;
        __syncthreads();
    }
}

extern "C" void kernel_launch(void* const* d_in, const int* in_sizes, int n_in,
                              void* d_out, int out_size, void* d_ws, size_t ws_size,
                              hipStream_t stream) {
    const float* x     = (const float*)d_in[0];
    const int*   eidx  = (const int*)d_in[1];
    const float* eattr = (const float*)d_in[2];
    const float* eW1   = (const float*)d_in[3];
    const float* eb1   = (const float*)d_in[4];
    const float* eW2   = (const float*)d_in[5];
    const float* eb2   = (const float*)d_in[6];
    const float* nW1   = (const float*)d_in[7];
    const float* nb1   = (const float*)d_in[8];
    const float* nW2   = (const float*)d_in[9];
    const float* nb2   = (const float*)d_in[10];

    char* ws = (char*)d_ws;
    int* counts   = (int*)(ws + WS_COUNTS);
    int* offsets  = (int*)(ws + WS_OFFSETS);
    int* cursor   = (int*)(ws + WS_CURSOR);
    int* bsum     = (int*)(ws + WS_BSUM);
    int* edge_ids = (int*)(ws + WS_EIDS);

    float* xout = (float*)d_out;
    float* eout = xout + (long)N_CNT * 64;

    hipMemsetAsync(counts, 0, 204800, stream);
    hist_kernel<<<1024, 256, 0, stream>>>(eidx, counts);
    scan_block_sums<<<SCAN_BLOCKS, 256, 0, stream>>>(counts, bsum);
    scan_top<<<1, 256, 0, stream>>>(bsum);
    scan_within<<<SCAN_BLOCKS, 256, 0, stream>>>(counts, bsum, offsets, cursor);
    scatter_kernel<<<1024, 256, 0, stream>>>(eidx, cursor, edge_ids);

    edge_kernel<<<2048, 256, 0, stream>>>(x, eidx, eattr, eW1, eb1, eW2, eb2, eout);
    node_kernel<<<1024, 256, 0, stream>>>(x, eout, offsets, counts, edge_ids,
                                          nW1, nb1, nW2, nb2, xout);
}